// Round 14
// baseline (534.526 us; speedup 1.0000x reference)
//
#include <hip/hip_runtime.h>
#include <hip/hip_bf16.h>
#include <stdint.h>

#define B_     32
#define CIN    128
#define COUT   128
#define KEXP   4
#define HW_    12544   // 112*112
#define SLABS  49      // 256-px slabs per sample
#define NU     (SLABS * B_)   // 1568 work units
#define NPT    392

typedef __attribute__((ext_vector_type(8))) short bf16x8;
typedef __attribute__((ext_vector_type(4))) float f32x4;
typedef __attribute__((ext_vector_type(16))) float f32x16;

static __device__ __forceinline__ short f2bf(float f) {
    __hip_bfloat16 h = __float2bfloat16(f);
    return __builtin_bit_cast(short, h);
}

// ===========================================================================
// SINGLE-PASS FUSED KERNEL (reads x once: 205MB in + 205MB out = 410MB floor)
//
// Work unit u = (b, slab of 256 px). Dynamic claim via atomic 'next' =>
// units processed in monotonic claim order => the lowest unfinished b's 49
// units are always held by resident blocks => deadlock-free spin.
//
// Per block:
//   1. each wave loads its 64-px chunk of x (fp32, coalesced f32x4),
//      accumulates per-cin pool partials, stages bf16 B-fragments into
//      wave-private LDS (XOR-swizzled), reads them back to registers.
//   2. fixed-point (x2^24) integer atomicAdd pool partials (deterministic),
//      threadfence, block counter release-increment.
//   3. spin on cnt[b]==49 (agent-scope acquire; bounded for hang safety).
//   4. agent-scope atomic loads of pooled -> gate softmax (redundant per
//      block) -> combine expert_w (L2-resident, read-only) into 32KB LDS
//      W-fragments (A-operand order).
//   5. mfma_32x32x16 (2 independent acc chains), nt stores (128B lines).
// ===========================================================================
__global__ __launch_bounds__(256, 2) void mono_kernel(
    const float* __restrict__ x,
    const float* __restrict__ gate_w,
    const float* __restrict__ gate_b,
    const float* __restrict__ expert_w,
    unsigned long long* __restrict__ pooled_fx,   // [B_][CIN] fixed-point sums
    int* __restrict__ cnt,                        // [B_]
    int* __restrict__ next,                       // work-unit counter
    float* __restrict__ out)
{
    __shared__ short wlds[4 * 8 * 512];     // 32 KB W fragments
    __shared__ char  xpriv_all[4][8192];    // 8 KB per wave: one 32-px tile
    __shared__ float plsh[CIN];
    __shared__ float logits[KEXP], gsh[KEXP];
    __shared__ int s_unit;

    const int t = threadIdx.x;
    if (t == 0) s_unit = atomicAdd(next, 1);
    __syncthreads();
    const int u  = s_unit;
    const int b  = u / SLABS;
    const int ug = u - b * SLABS;
    const int px0 = ug * 256;

    const int wave = t >> 6;
    const int lane = t & 63;
    const int pg2  = lane & 7;      // px quad group (0..7) -> px = pg2*4+p
    const int cg   = lane >> 3;     // 0..7 -> cins cg*16..+15 ; == fragment f
    char* xpriv = xpriv_all[wave];

    // ---- phase 1: load x, pool partials, stage B-fragments ----
    float poolacc[16];
    #pragma unroll
    for (int i = 0; i < 16; ++i) poolacc[i] = 0.f;

    bf16x8 bfrag[2][8];

    #pragma unroll
    for (int tt = 0; tt < 2; ++tt) {
        const float* __restrict__ xr = x + (size_t)b * CIN * HW_
            + (size_t)(cg * 16) * HW_ + px0 + wave * 64 + tt * 32 + pg2 * 4;
        f32x4 va[16];
        #pragma unroll
        for (int i = 0; i < 16; ++i)
            va[i] = *(const f32x4*)(xr + (size_t)i * HW_);

        #pragma unroll
        for (int i = 0; i < 16; ++i)
            poolacc[i] += (va[i][0] + va[i][1]) + (va[i][2] + va[i][3]);

        // stage to wave-private LDS in fragment order (slot ^= cg swizzle)
        #pragma unroll
        for (int p = 0; p < 4; ++p) {
            bf16x8 lo, hi;
            #pragma unroll
            for (int i = 0; i < 8; ++i) { lo[i] = f2bf(va[i][p]); hi[i] = f2bf(va[8 + i][p]); }
            const int pxl = pg2 * 4 + p;
            *(bf16x8*)(xpriv + cg * 1024 + ((pxl      ^ cg) << 4)) = lo;
            *(bf16x8*)(xpriv + cg * 1024 + (((32+pxl) ^ cg) << 4)) = hi;
        }
        #pragma unroll
        for (int f = 0; f < 8; ++f)
            bfrag[tt][f] = *(const bf16x8*)(xpriv + f * 1024 + ((lane ^ f) << 4));
    }

    // ---- phase 2: pooling atomics (fixed-point, deterministic) ----
    #pragma unroll
    for (int m = 1; m < 8; m <<= 1) {
        #pragma unroll
        for (int i = 0; i < 16; ++i) poolacc[i] += __shfl_xor(poolacc[i], m, 64);
    }
    if (pg2 == 0) {
        #pragma unroll
        for (int i = 0; i < 16; ++i) {
            long long q = llrintf(poolacc[i] * 16777216.0f);   // *2^24
            atomicAdd(&pooled_fx[b * CIN + cg * 16 + i], (unsigned long long)q);
        }
    }
    __threadfence();
    __syncthreads();
    if (t == 0)
        __hip_atomic_fetch_add(&cnt[b], 1, __ATOMIC_RELEASE, __HIP_MEMORY_SCOPE_AGENT);

    // ---- phase 3: spin until all 49 slabs of b contributed ----
    if (t == 0) {
        for (int it = 0; it < (1 << 21); ++it) {
            if (__hip_atomic_load(&cnt[b], __ATOMIC_ACQUIRE, __HIP_MEMORY_SCOPE_AGENT) >= SLABS)
                break;
            __builtin_amdgcn_s_sleep(16);
        }
    }
    __syncthreads();

    // ---- phase 4: gate (redundant per block) ----
    if (t < CIN) {
        unsigned long long q = __hip_atomic_load(&pooled_fx[b * CIN + t],
                                                 __ATOMIC_RELAXED, __HIP_MEMORY_SCOPE_AGENT);
        plsh[t] = (float)((double)(long long)q * (1.0 / 16777216.0) * (1.0 / HW_));
    }
    __syncthreads();
    {
        const int wid = t >> 6;
        float s = plsh[lane] * gate_w[wid * CIN + lane]
                + plsh[64 + lane] * gate_w[wid * CIN + 64 + lane];
        #pragma unroll
        for (int off = 32; off > 0; off >>= 1) s += __shfl_down(s, off, 64);
        if (lane == 0) logits[wid] = s + gate_b[wid];
    }
    __syncthreads();
    if (t == 0) {
        float m = fmaxf(fmaxf(logits[0], logits[1]), fmaxf(logits[2], logits[3]));
        float e0 = expf(logits[0] - m), e1 = expf(logits[1] - m);
        float e2 = expf(logits[2] - m), e3 = expf(logits[3] - m);
        float inv = 1.f / (e0 + e1 + e2 + e3);
        gsh[0] = e0 * inv; gsh[1] = e1 * inv; gsh[2] = e2 * inv; gsh[3] = e3 * inv;
    }
    __syncthreads();
    {
        const float g0 = gsh[0], g1 = gsh[1], g2 = gsh[2], g3 = gsh[3];
        for (int idx = t; idx < COUT * CIN; idx += 256) {
            float w = g0 * expert_w[idx]
                    + g1 * expert_w[COUT * CIN + idx]
                    + g2 * expert_w[2 * COUT * CIN + idx]
                    + g3 * expert_w[3 * COUT * CIN + idx];
            const int o = idx >> 7, c = idx & 127;
            const int dst = ((o >> 5) * 8 + (c >> 4)) * 512
                          + (((c >> 3) & 1) * 32 + (o & 31)) * 8 + (c & 7);
            wlds[dst] = f2bf(w);
        }
    }
    __syncthreads();

    // ---- phase 5: MFMA + nt stores (conv4 body) ----
    const int pt0 = ug * 8 + wave * 2;
    const int rowadd = 4 * (lane >> 5);
    float* __restrict__ ob0 = out + (size_t)b * COUT * HW_ + pt0 * 32 + (lane & 31);
    float* __restrict__ ob1 = ob0 + 32;

    #pragma unroll
    for (int ct = 0; ct < 4; ++ct) {
        f32x16 a0, a1;
        #pragma unroll
        for (int r = 0; r < 16; ++r) { a0[r] = 0.f; a1[r] = 0.f; }

        const short* __restrict__ wl = wlds + (ct * 8) * 512 + lane * 8;
        #pragma unroll
        for (int f = 0; f < 8; ++f) {
            bf16x8 afrag = *(const bf16x8*)(wl + f * 512);
            a0 = __builtin_amdgcn_mfma_f32_32x32x16_bf16(afrag, bfrag[0][f], a0, 0, 0, 0);
            a1 = __builtin_amdgcn_mfma_f32_32x32x16_bf16(afrag, bfrag[1][f], a1, 0, 0, 0);
        }
        #pragma unroll
        for (int r = 0; r < 16; ++r) {
            const int cout = ct * 32 + (r & 3) + 8 * (r >> 2) + rowadd;
            __builtin_nontemporal_store(a0[r], ob0 + (size_t)cout * HW_);
            __builtin_nontemporal_store(a1[r], ob1 + (size_t)cout * HW_);
        }
    }
}

// ===========================================================================
// FALLBACK (ws too small) — round-2 proven structure
// ===========================================================================

__global__ __launch_bounds__(256) void pool_kernel(const float* __restrict__ x,
                                                   float* __restrict__ pooled) {
    const int row = blockIdx.x;
    const float4* __restrict__ x4 = (const float4*)(x + (size_t)row * HW_);
    const int t = threadIdx.x;
    float s = 0.f;
    for (int idx = t; idx < HW_ / 4; idx += 256) {
        float4 v = x4[idx];
        s += (v.x + v.y) + (v.z + v.w);
    }
    #pragma unroll
    for (int off = 32; off > 0; off >>= 1) s += __shfl_down(s, off, 64);
    __shared__ float wsum[4];
    if ((t & 63) == 0) wsum[t >> 6] = s;
    __syncthreads();
    if (t == 0) pooled[row] = (wsum[0] + wsum[1] + wsum[2] + wsum[3]) * (1.0f / HW_);
}

__global__ __launch_bounds__(256) void gate_kernel(const float* __restrict__ pooled,
                                                   const float* __restrict__ gate_w,
                                                   const float* __restrict__ gate_b,
                                                   const float* __restrict__ expert_w,
                                                   short* __restrict__ wmix) {
    const int b = blockIdx.x;
    const int t = threadIdx.x;
    const int wid = t >> 6, lane = t & 63;
    __shared__ float logits[KEXP];
    __shared__ float gsh[KEXP];
    {
        float p0 = pooled[b * CIN + lane];
        float p1 = pooled[b * CIN + 64 + lane];
        float s = p0 * gate_w[wid * CIN + lane] + p1 * gate_w[wid * CIN + 64 + lane];
        #pragma unroll
        for (int off = 32; off > 0; off >>= 1) s += __shfl_down(s, off, 64);
        if (lane == 0) logits[wid] = s + gate_b[wid];
    }
    __syncthreads();
    if (t == 0) {
        float m = fmaxf(fmaxf(logits[0], logits[1]), fmaxf(logits[2], logits[3]));
        float e0 = expf(logits[0] - m), e1 = expf(logits[1] - m);
        float e2 = expf(logits[2] - m), e3 = expf(logits[3] - m);
        float inv = 1.f / (e0 + e1 + e2 + e3);
        gsh[0] = e0 * inv; gsh[1] = e1 * inv; gsh[2] = e2 * inv; gsh[3] = e3 * inv;
    }
    __syncthreads();
    const float g0 = gsh[0], g1 = gsh[1], g2 = gsh[2], g3 = gsh[3];
    for (int idx = t; idx < COUT * CIN; idx += 256) {
        float w = g0 * expert_w[idx]
                + g1 * expert_w[COUT * CIN + idx]
                + g2 * expert_w[2 * COUT * CIN + idx]
                + g3 * expert_w[3 * COUT * CIN + idx];
        wmix[b * COUT * CIN + idx] = f2bf(w);
    }
}

__global__ __launch_bounds__(256, 4) void conv_fb_kernel(const float* __restrict__ x,
                                                         const short* __restrict__ wmix,
                                                         float* __restrict__ out) {
    __shared__ char wlds[COUT * 256];
    __shared__ char xlds[64 * 256];
    const int b  = blockIdx.y;
    const int p0 = blockIdx.x * 64;
    const int t  = threadIdx.x;

    {
        const uint4* __restrict__ wsrc = (const uint4*)(wmix + (size_t)b * COUT * CIN);
        #pragma unroll
        for (int pass = 0; pass < 8; ++pass) {
            int o  = (t >> 4) + pass * 16;
            int i4 = t & 15;
            uint4 v = wsrc[o * 16 + i4];
            *(uint4*)(wlds + o * 256 + ((i4 ^ (o & 15)) << 4)) = v;
        }
    }
    {
        const int pg = t & 15;
        const int cg = t >> 4;
        #pragma unroll
        for (int p = 0; p < 2; ++p) {
            const int cin0 = p * 64 + cg * 4;
            const float* xrow = x + (size_t)b * CIN * HW_ + (size_t)cin0 * HW_ + p0 + pg * 4;
            float va[4][4];
            #pragma unroll
            for (int i = 0; i < 4; ++i) {
                float4 v = *(const float4*)(xrow + (size_t)i * HW_);
                va[i][0] = v.x; va[i][1] = v.y; va[i][2] = v.z; va[i][3] = v.w;
            }
            #pragma unroll
            for (int j = 0; j < 4; ++j) {
                const int pix = pg * 4 + j;
                uint32_t lo = (uint32_t)(ushort)f2bf(va[0][j]) | ((uint32_t)(ushort)f2bf(va[1][j]) << 16);
                uint32_t hi = (uint32_t)(ushort)f2bf(va[2][j]) | ((uint32_t)(ushort)f2bf(va[3][j]) << 16);
                int byte = (pix * 256 + cin0 * 2) ^ ((pix & 7) << 4);
                uint2 w2; w2.x = lo; w2.y = hi;
                *(uint2*)(xlds + byte) = w2;
            }
        }
    }

    const int wave = t >> 6;
    const int lane = t & 63;
    const int n = lane & 15;
    const int h = lane >> 4;

    __syncthreads();

    bf16x8 xfrag[4];
    {
        const int pixl = wave * 16 + n;
        #pragma unroll
        for (int kk = 0; kk < 4; ++kk) {
            int byte = (pixl * 256 + kk * 64 + h * 16) ^ ((pixl & 7) << 4);
            xfrag[kk] = *(const bf16x8*)(xlds + byte);
        }
    }

    f32x4 acc[8];
    #pragma unroll
    for (int ot = 0; ot < 8; ++ot) acc[ot] = (f32x4){0.f, 0.f, 0.f, 0.f};

    #pragma unroll
    for (int ot = 0; ot < 8; ++ot) {
        const int o = ot * 16 + n;
        #pragma unroll
        for (int kk = 0; kk < 4; ++kk) {
            bf16x8 wfrag = *(const bf16x8*)(wlds + o * 256 + (((kk * 4 + h) ^ n) << 4));
            acc[ot] = __builtin_amdgcn_mfma_f32_16x16x32_bf16(xfrag[kk], wfrag, acc[ot], 0, 0, 0);
        }
    }

    float* __restrict__ ob = out + (size_t)b * COUT * HW_ + p0 + wave * 16 + h * 4;
    #pragma unroll
    for (int ot = 0; ot < 8; ++ot)
        __builtin_nontemporal_store(acc[ot], (f32x4*)(ob + (size_t)(ot * 16 + n) * HW_));
}

// ---------------------------------------------------------------------------
extern "C" void kernel_launch(void* const* d_in, const int* in_sizes, int n_in,
                              void* d_out, int out_size, void* d_ws, size_t ws_size,
                              hipStream_t stream) {
    const float* x        = (const float*)d_in[0];
    const float* expert_w = (const float*)d_in[1];
    const float* gate_w   = (const float*)d_in[2];
    const float* gate_b   = (const float*)d_in[3];
    float* out = (float*)d_out;

    // ws: [pooled_fx: 32KB][cnt: 128B][next: 4B]
    const size_t POOL_B = (size_t)B_ * CIN * 8;     // 32768
    const size_t CNT_B  = 128;
    const size_t NEED   = POOL_B + CNT_B + 64;

    if (ws_size >= NEED) {
        unsigned long long* pooled_fx = (unsigned long long*)d_ws;
        int* cnt  = (int*)((char*)d_ws + POOL_B);
        int* next = (int*)((char*)d_ws + POOL_B + CNT_B);

        hipMemsetAsync(d_ws, 0, NEED, stream);      // deterministic per launch
        mono_kernel<<<dim3(NU), 256, 0, stream>>>(
            x, gate_w, gate_b, expert_w, pooled_fx, cnt, next, out);
    } else {
        float* pooled = (float*)d_ws;
        short* wmix   = (short*)((char*)d_ws + 16384);
        pool_kernel<<<dim3(B_ * CIN), 256, 0, stream>>>(x, pooled);
        gate_kernel<<<dim3(B_), 256, 0, stream>>>(pooled, gate_w, gate_b, expert_w, wmix);
        conv_fb_kernel<<<dim3(HW_ / 64, B_), 256, 0, stream>>>(x, wmix, out);
    }
}

// Round 15
// 130.554 us; speedup vs baseline: 4.0943x; 4.0943x over previous
//
#include <hip/hip_runtime.h>
#include <hip/hip_bf16.h>
#include <stdint.h>

#define B_     32
#define CIN    128
#define COUT   128
#define KEXP   4
#define HW_    12544   // 112*112
#define NCHUNK 196     // 64-px chunks per b
#define NPT    392     // 32-px tiles per b

typedef __attribute__((ext_vector_type(8))) short bf16x8;
typedef __attribute__((ext_vector_type(4))) float f32x4;
typedef __attribute__((ext_vector_type(16))) float f32x16;

// fp32 -> bf16 RNE via native conversion
static __device__ __forceinline__ short f2bf(float f) {
    __hip_bfloat16 h = __float2bfloat16(f);
    return __builtin_bit_cast(short, h);
}

// ===========================================================================
// FAST PATH: 2 kernels.
//   prep : x -> xbf2 (B-fragment-ordered bf16) + partial pooling sums
//   convg: inline gate (redundant per block, L2-resident inputs) + MFMA conv
// xbf2 layout: [b][pt=px>>5][f=cin>>4][lane][j]
//   (lane = ((cin>>3)&1)*32 + (px&31), j = cin&7)
// W fragments (LDS): [ct=cout>>5][f][lane][j] (lane = ((cin>>3)&1)*32+(cout&31))
// ===========================================================================

// ---------------------------------------------------------------------------
// prep: identical to R12 (129.7us best). Reads x once, coalesced f32x4.
// ---------------------------------------------------------------------------
__global__ __launch_bounds__(256) void prep_kernel(const float* __restrict__ x,
                                                   short* __restrict__ xbf2,
                                                   float* __restrict__ partial) {
    const int b  = blockIdx.y;
    const int cx = blockIdx.x;              // 0..195
    const int p0 = cx * 64;
    const int t  = threadIdx.x;
    const int pg  = t & 15;                 // pixel quad (0..15)
    const int cg8 = t >> 4;                 // cin octet (0..15)

    const float* __restrict__ xr = x + (size_t)b * CIN * HW_
                                 + (size_t)(cg8 * 8) * HW_ + p0 + pg * 4;
    f32x4 va[8];
    #pragma unroll
    for (int i = 0; i < 8; ++i)
        va[i] = *(const f32x4*)(xr + (size_t)i * HW_);

    float ps[8];
    #pragma unroll
    for (int i = 0; i < 8; ++i) ps[i] = (va[i][0] + va[i][1]) + (va[i][2] + va[i][3]);
    #pragma unroll
    for (int m = 1; m < 16; m <<= 1) {
        #pragma unroll
        for (int i = 0; i < 8; ++i) ps[i] += __shfl_xor(ps[i], m, 64);
    }
    if (pg == 0) {
        float* pdst = partial + ((size_t)b * NCHUNK + cx) * CIN + cg8 * 8;
        f32x4 v0 = {ps[0], ps[1], ps[2], ps[3]};
        f32x4 v1 = {ps[4], ps[5], ps[6], ps[7]};
        *(f32x4*)pdst = v0;
        *(f32x4*)(pdst + 4) = v1;
    }

    short* __restrict__ xd = xbf2
        + ((size_t)(b * NPT + cx * 2 + (pg >> 3)) * 8 + (cg8 >> 1)) * 512
        + ((cg8 & 1) * 32 + (pg & 7) * 4) * 8;
    #pragma unroll
    for (int jj = 0; jj < 4; ++jj) {
        bf16x8 pk;
        #pragma unroll
        for (int i = 0; i < 8; ++i) pk[i] = f2bf(va[i][jj]);
        *(bf16x8*)(xd + jj * 8) = pk;
    }
}

// ---------------------------------------------------------------------------
// convg: per block (ug, b):
//   0. issue 16 B-fragment global loads (HBM/L3) -- consumed in phase 3,
//      latency hidden under the gate phase.
//   1. gate: reduce partial[b] (3.2MB total, L2-resident) -> pooled ->
//      softmax -> combine expert_w (256KB, L2-resident) into 32KB LDS
//      W-fragments.  Redundant per block; replaces the gate2 dispatch.
//   2. barrier (wlds ready)
//   3. mfma_32x32x16 x2 independent chains; nt dword stores (2 full 128B
//      lines per instruction).
// Coherence: partial/xbf2 produced by prep (kernel boundary = coherent);
// everything else read-only inputs. No intra-kernel cross-block deps.
// ---------------------------------------------------------------------------
__global__ __launch_bounds__(256, 3) void convg_kernel(const short* __restrict__ xbf2,
                                                       const float* __restrict__ partial,
                                                       const float* __restrict__ gate_w,
                                                       const float* __restrict__ gate_b,
                                                       const float* __restrict__ expert_w,
                                                       float* __restrict__ out) {
    __shared__ short wlds[4 * 8 * 512];         // 32 KB W fragments
    __shared__ float psum[2][CIN];
    __shared__ float pl[CIN];
    __shared__ float logits[KEXP], gsh[KEXP];

    const int t = threadIdx.x;
    const int b = (B_ - 1) - blockIdx.y;        // LIFO vs prep write order

    // bijective XCD swizzle (nwg=49: q=6, r=1), reversed
    const int orig = blockIdx.x;
    const int xcd = orig & 7, idx = orig >> 3;
    const int wgid = (xcd < 1 ? xcd * 7 : 7 + (xcd - 1) * 6) + idx;
    const int ug = 48 - wgid;

    const int wave = t >> 6;
    const int lane = t & 63;
    const int pt0  = ug * 8 + wave * 2;

    // ---- phase 0: hoisted B-fragment loads (1KB dense per instruction) ----
    const short* __restrict__ xb = xbf2 + ((size_t)(b * NPT + pt0) * 8) * 512 + lane * 8;
    bf16x8 b0f[8], b1f[8];
    #pragma unroll
    for (int f = 0; f < 8; ++f) b0f[f] = *(const bf16x8*)(xb + f * 512);
    #pragma unroll
    for (int f = 0; f < 8; ++f) b1f[f] = *(const bf16x8*)(xb + (8 + f) * 512);

    // ---- phase 1: inline gate ----
    {
        const int cin  = t & 127;
        const int half = t >> 7;
        float s = 0.f;
        const float* pp = partial + (size_t)b * NCHUNK * CIN + (size_t)(half * 98) * CIN + cin;
        #pragma unroll 7
        for (int c = 0; c < 98; ++c) s += pp[(size_t)c * CIN];
        psum[half][cin] = s;
    }
    __syncthreads();
    if (t < CIN) pl[t] = (psum[0][t] + psum[1][t]) * (1.0f / HW_);
    __syncthreads();
    {
        const int wid = t >> 6;
        float s = pl[lane] * gate_w[wid * CIN + lane]
                + pl[64 + lane] * gate_w[wid * CIN + 64 + lane];
        #pragma unroll
        for (int off = 32; off > 0; off >>= 1) s += __shfl_down(s, off, 64);
        if (lane == 0) logits[wid] = s + gate_b[wid];
    }
    __syncthreads();
    if (t == 0) {
        float m = fmaxf(fmaxf(logits[0], logits[1]), fmaxf(logits[2], logits[3]));
        float e0 = expf(logits[0] - m), e1 = expf(logits[1] - m);
        float e2 = expf(logits[2] - m), e3 = expf(logits[3] - m);
        float inv = 1.f / (e0 + e1 + e2 + e3);
        gsh[0] = e0 * inv; gsh[1] = e1 * inv; gsh[2] = e2 * inv; gsh[3] = e3 * inv;
    }
    __syncthreads();
    {
        const float g0 = gsh[0], g1 = gsh[1], g2 = gsh[2], g3 = gsh[3];
        for (int idx2 = t; idx2 < COUT * CIN; idx2 += 256) {
            float w = g0 * expert_w[idx2]
                    + g1 * expert_w[COUT * CIN + idx2]
                    + g2 * expert_w[2 * COUT * CIN + idx2]
                    + g3 * expert_w[3 * COUT * CIN + idx2];
            const int o = idx2 >> 7, c = idx2 & 127;   // cout, cin
            const int dst = ((o >> 5) * 8 + (c >> 4)) * 512
                          + (((c >> 3) & 1) * 32 + (o & 31)) * 8 + (c & 7);
            wlds[dst] = f2bf(w);
        }
    }
    __syncthreads();                            // wlds ready

    // ---- phase 3: MFMA + full-line nt stores ----
    const int rowadd = 4 * (lane >> 5);
    float* __restrict__ ob0 = out + (size_t)b * COUT * HW_ + pt0 * 32 + (lane & 31);
    float* __restrict__ ob1 = ob0 + 32;

    #pragma unroll
    for (int ct = 0; ct < 4; ++ct) {
        f32x16 a0, a1;
        #pragma unroll
        for (int r = 0; r < 16; ++r) { a0[r] = 0.f; a1[r] = 0.f; }

        const short* __restrict__ wl = wlds + (ct * 8) * 512 + lane * 8;
        #pragma unroll
        for (int f = 0; f < 8; ++f) {
            bf16x8 afrag = *(const bf16x8*)(wl + f * 512);
            a0 = __builtin_amdgcn_mfma_f32_32x32x16_bf16(afrag, b0f[f], a0, 0, 0, 0);
            a1 = __builtin_amdgcn_mfma_f32_32x32x16_bf16(afrag, b1f[f], a1, 0, 0, 0);
        }
        #pragma unroll
        for (int r = 0; r < 16; ++r) {
            const int cout = ct * 32 + (r & 3) + 8 * (r >> 2) + rowadd;
            __builtin_nontemporal_store(a0[r], ob0 + (size_t)cout * HW_);
            __builtin_nontemporal_store(a1[r], ob1 + (size_t)cout * HW_);
        }
    }
}

// ===========================================================================
// FALLBACK PATH (round-2 structure) - used if ws too small
// ===========================================================================

__global__ __launch_bounds__(256) void pool_kernel(const float* __restrict__ x,
                                                   float* __restrict__ pooled) {
    const int row = blockIdx.x;
    const float4* __restrict__ x4 = (const float4*)(x + (size_t)row * HW_);
    const int t = threadIdx.x;
    float s = 0.f;
    for (int idx = t; idx < HW_ / 4; idx += 256) {
        float4 v = x4[idx];
        s += (v.x + v.y) + (v.z + v.w);
    }
    #pragma unroll
    for (int off = 32; off > 0; off >>= 1) s += __shfl_down(s, off, 64);
    __shared__ float wsum[4];
    if ((t & 63) == 0) wsum[t >> 6] = s;
    __syncthreads();
    if (t == 0) pooled[row] = (wsum[0] + wsum[1] + wsum[2] + wsum[3]) * (1.0f / HW_);
}

__global__ __launch_bounds__(256) void gate_kernel(const float* __restrict__ pooled,
                                                   const float* __restrict__ gate_w,
                                                   const float* __restrict__ gate_b,
                                                   const float* __restrict__ expert_w,
                                                   short* __restrict__ wmix) {
    const int b = blockIdx.x;
    const int t = threadIdx.x;
    const int wid = t >> 6, lane = t & 63;
    __shared__ float logits[KEXP];
    __shared__ float gsh[KEXP];
    {
        float p0 = pooled[b * CIN + lane];
        float p1 = pooled[b * CIN + 64 + lane];
        float s = p0 * gate_w[wid * CIN + lane] + p1 * gate_w[wid * CIN + 64 + lane];
        #pragma unroll
        for (int off = 32; off > 0; off >>= 1) s += __shfl_down(s, off, 64);
        if (lane == 0) logits[wid] = s + gate_b[wid];
    }
    __syncthreads();
    if (t == 0) {
        float m = fmaxf(fmaxf(logits[0], logits[1]), fmaxf(logits[2], logits[3]));
        float e0 = expf(logits[0] - m), e1 = expf(logits[1] - m);
        float e2 = expf(logits[2] - m), e3 = expf(logits[3] - m);
        float inv = 1.f / (e0 + e1 + e2 + e3);
        gsh[0] = e0 * inv; gsh[1] = e1 * inv; gsh[2] = e2 * inv; gsh[3] = e3 * inv;
    }
    __syncthreads();
    const float g0 = gsh[0], g1 = gsh[1], g2 = gsh[2], g3 = gsh[3];
    for (int idx = t; idx < COUT * CIN; idx += 256) {
        float w = g0 * expert_w[idx]
                + g1 * expert_w[COUT * CIN + idx]
                + g2 * expert_w[2 * COUT * CIN + idx]
                + g3 * expert_w[3 * COUT * CIN + idx];
        wmix[b * COUT * CIN + idx] = f2bf(w);
    }
}

__global__ __launch_bounds__(256, 4) void conv_fb_kernel(const float* __restrict__ x,
                                                         const short* __restrict__ wmix,
                                                         float* __restrict__ out) {
    __shared__ char wlds[COUT * 256];
    __shared__ char xlds[64 * 256];
    const int b  = blockIdx.y;
    const int p0 = blockIdx.x * 64;
    const int t  = threadIdx.x;

    {
        const uint4* __restrict__ wsrc = (const uint4*)(wmix + (size_t)b * COUT * CIN);
        #pragma unroll
        for (int pass = 0; pass < 8; ++pass) {
            int o  = (t >> 4) + pass * 16;
            int i4 = t & 15;
            uint4 v = wsrc[o * 16 + i4];
            *(uint4*)(wlds + o * 256 + ((i4 ^ (o & 15)) << 4)) = v;
        }
    }
    {
        const int pg = t & 15;
        const int cg = t >> 4;
        #pragma unroll
        for (int p = 0; p < 2; ++p) {
            const int cin0 = p * 64 + cg * 4;
            const float* xrow = x + (size_t)b * CIN * HW_ + (size_t)cin0 * HW_ + p0 + pg * 4;
            float va[4][4];
            #pragma unroll
            for (int i = 0; i < 4; ++i) {
                float4 v = *(const float4*)(xrow + (size_t)i * HW_);
                va[i][0] = v.x; va[i][1] = v.y; va[i][2] = v.z; va[i][3] = v.w;
            }
            #pragma unroll
            for (int j = 0; j < 4; ++j) {
                const int pix = pg * 4 + j;
                uint32_t lo = (uint32_t)(ushort)f2bf(va[0][j]) | ((uint32_t)(ushort)f2bf(va[1][j]) << 16);
                uint32_t hi = (uint32_t)(ushort)f2bf(va[2][j]) | ((uint32_t)(ushort)f2bf(va[3][j]) << 16);
                int byte = (pix * 256 + cin0 * 2) ^ ((pix & 7) << 4);
                uint2 w2; w2.x = lo; w2.y = hi;
                *(uint2*)(xlds + byte) = w2;
            }
        }
    }

    const int wave = t >> 6;
    const int lane = t & 63;
    const int n = lane & 15;
    const int h = lane >> 4;

    __syncthreads();

    bf16x8 xfrag[4];
    {
        const int pixl = wave * 16 + n;
        #pragma unroll
        for (int kk = 0; kk < 4; ++kk) {
            int byte = (pixl * 256 + kk * 64 + h * 16) ^ ((pixl & 7) << 4);
            xfrag[kk] = *(const bf16x8*)(xlds + byte);
        }
    }

    f32x4 acc[8];
    #pragma unroll
    for (int ot = 0; ot < 8; ++ot) acc[ot] = (f32x4){0.f, 0.f, 0.f, 0.f};

    #pragma unroll
    for (int ot = 0; ot < 8; ++ot) {
        const int o = ot * 16 + n;
        #pragma unroll
        for (int kk = 0; kk < 4; ++kk) {
            bf16x8 wfrag = *(const bf16x8*)(wlds + o * 256 + (((kk * 4 + h) ^ n) << 4));
            acc[ot] = __builtin_amdgcn_mfma_f32_16x16x32_bf16(xfrag[kk], wfrag, acc[ot], 0, 0, 0);
        }
    }

    float* __restrict__ ob = out + (size_t)b * COUT * HW_ + p0 + wave * 16 + h * 4;
    #pragma unroll
    for (int ot = 0; ot < 8; ++ot)
        __builtin_nontemporal_store(acc[ot], (f32x4*)(ob + (size_t)(ot * 16 + n) * HW_));
}

// ---------------------------------------------------------------------------
extern "C" void kernel_launch(void* const* d_in, const int* in_sizes, int n_in,
                              void* d_out, int out_size, void* d_ws, size_t ws_size,
                              hipStream_t stream) {
    const float* x        = (const float*)d_in[0];
    const float* expert_w = (const float*)d_in[1];
    const float* gate_w   = (const float*)d_in[2];
    const float* gate_b   = (const float*)d_in[3];
    float* out = (float*)d_out;

    const size_t PARTIAL_B = (size_t)B_ * NCHUNK * CIN * 4;     // 3,211,264
    const size_t XBF_B     = (size_t)B_ * HW_ * CIN * 2;        // 102,760,448
    const size_t NEED      = PARTIAL_B + XBF_B;

    if (ws_size >= NEED) {
        float* partial = (float*)d_ws;
        short* xbf2    = (short*)((char*)d_ws + PARTIAL_B);

        prep_kernel<<<dim3(NCHUNK, B_), 256, 0, stream>>>(x, xbf2, partial);
        convg_kernel<<<dim3(49, B_), 256, 0, stream>>>(xbf2, partial, gate_w,
                                                       gate_b, expert_w, out);
    } else {
        float* pooled = (float*)d_ws;                           // 16 KB
        short* wmix   = (short*)((char*)d_ws + 16384);          // 1 MB
        pool_kernel<<<dim3(B_ * CIN), 256, 0, stream>>>(x, pooled);
        gate_kernel<<<dim3(B_), 256, 0, stream>>>(pooled, gate_w, gate_b, expert_w, wmix);
        conv_fb_kernel<<<dim3(HW_ / 64, B_), 256, 0, stream>>>(x, wmix, out);
    }
}